// Round 1
// baseline (106.885 us; speedup 1.0000x reference)
//
#include <hip/hip_runtime.h>
#include <math.h>

#define B_   8
#define T_   4096
#define D_   1024
#define LCH  64               // chunk length along T
#define CCH  (T_/LCH)         // 64 chunks
#define BD   (B_*D_)          // 8192
#define EPS_ 1e-5f

__device__ __forceinline__ float gelu_f(float x) {
    const float c = 0.7978845608028654f;  // sqrt(2/pi)
    float x3 = x * x * x;
    float y  = c * (x + 0.044715f * x3);
    // tanh(y) = 1 - 2/(1+exp(2y)); stable at both tails
    float e  = __expf(2.0f * y);
    float th = 1.0f - 2.0f / (1.0f + e);
    return 0.5f * x * (1.0f + th);
}

__device__ __forceinline__ float sigmoid_f(float z) {
    return 1.0f / (1.0f + __expf(-z));
}

// K1: per (b, d, chunk) compute S = sum_i d^(L-1-i) * (1-d) * |gelu(x_t)|
__global__ __launch_bounds__(1024) void k1_chunksum(
        const float* __restrict__ x,
        const float* __restrict__ logit_d_ca,
        float* __restrict__ S) {
    const int c = blockIdx.x, b = blockIdx.y, d = threadIdx.x;
    const float dca  = sigmoid_f(logit_d_ca[0]);
    const float omd  = 1.0f - dca;
    const float* xp = x + ((size_t)b * T_ + (size_t)c * LCH) * D_ + d;
    float s = 0.0f;
    #pragma unroll 4
    for (int i = 0; i < LCH; ++i) {
        float f = fabsf(gelu_f(xp[(size_t)i * D_]));
        s = dca * s + omd * f;
    }
    S[(size_t)c * BD + (size_t)b * D_ + d] = s;
}

// K2: sequential chain over chunks; converts S[c] (chunk sums) into
// Ca_start[c] (Ca value at the beginning of chunk c), in place.
__global__ __launch_bounds__(256) void k2_chain(
        const float* __restrict__ logit_d_ca,
        const float* __restrict__ ema,
        float* __restrict__ S) {
    const int idx = blockIdx.x * 256 + threadIdx.x;  // = b*D + d
    if (idx >= BD) return;
    const int d = idx & (D_ - 1);
    const float dca = sigmoid_f(logit_d_ca[0]);
    float dL = dca;
    #pragma unroll
    for (int k = 0; k < 6; ++k) dL *= dL;  // dca^64
    float Ca = ema[d];
    for (int c = 0; c < CCH; ++c) {
        float s = S[(size_t)c * BD + idx];
        S[(size_t)c * BD + idx] = Ca;   // Ca at start of chunk c
        Ca = dL * Ca + s;               // Ca at start of chunk c+1
    }
}

// K3: per (b, chunk) block; thread d scans the chunk, block-reduces the
// gate sum over D each step, writes out = gelu(x) * gate / (mean+eps).
__global__ __launch_bounds__(1024) void k3_final(
        const float* __restrict__ x,
        const float* __restrict__ log_beta_raw,
        const float* __restrict__ logit_d_ca,
        const float* __restrict__ CaS,
        float* __restrict__ out) {
    const int c = blockIdx.x, b = blockIdx.y, d = threadIdx.x;
    const int wave = threadIdx.x >> 6, lane = threadIdx.x & 63;
    __shared__ float red[2][16];

    const float lbr  = log_beta_raw[0];
    const float beta = (lbr > 20.0f) ? lbr : log1pf(__expf(lbr));
    const float dca  = sigmoid_f(logit_d_ca[0]);
    const float omd  = 1.0f - dca;

    float Ca = CaS[(size_t)c * BD + (size_t)b * D_ + d];
    const size_t base = ((size_t)b * T_ + (size_t)c * LCH) * D_ + d;

    float xv = x[base];
    for (int i = 0; i < LCH; ++i) {
        // issue next load early so HBM latency hides across the barrier
        float xnext = (i + 1 < LCH) ? x[base + (size_t)(i + 1) * D_] : 0.0f;

        float o    = gelu_f(xv);
        float f    = fabsf(o);
        float gate = 1.0f / (1.0f + beta * Ca);

        // block-wide sum of gate over 1024 threads
        float gsum = gate;
        #pragma unroll
        for (int m = 32; m >= 1; m >>= 1) gsum += __shfl_xor(gsum, m, 64);
        const int p = i & 1;                  // double-buffer: 1 barrier/iter
        if (lane == 0) red[p][wave] = gsum;
        __syncthreads();
        float tot = 0.0f;
        #pragma unroll
        for (int w = 0; w < 16; ++w) tot += red[p][w];
        float mean = tot * (1.0f / (float)D_);

        out[base + (size_t)i * D_] = o * gate / (mean + EPS_);

        Ca = dca * Ca + omd * f;
        xv = xnext;
    }
}

extern "C" void kernel_launch(void* const* d_in, const int* in_sizes, int n_in,
                              void* d_out, int out_size, void* d_ws, size_t ws_size,
                              hipStream_t stream) {
    const float* x    = (const float*)d_in[0];
    const float* lbr  = (const float*)d_in[1];
    const float* ldc  = (const float*)d_in[2];
    // d_in[3] (logit_decay) is unused by the steady-state reference path
    const float* ema  = (const float*)d_in[4];
    float* S   = (float*)d_ws;   // C * B * D floats = 2 MiB
    float* out = (float*)d_out;

    dim3 grid(CCH, B_);
    k1_chunksum<<<grid, 1024, 0, stream>>>(x, ldc, S);
    k2_chain<<<BD / 256, 256, 0, stream>>>(ldc, ema, S);
    k3_final<<<grid, 1024, 0, stream>>>(x, lbr, ldc, S, out);
}